// Round 7
// baseline (118.002 us; speedup 1.0000x reference)
//
#include <hip/hip_runtime.h>

#define NH 6
#define HEAD_DIM 32
#define CCH 192
#define HH 56
#define WW 56
#define HWSZ (HH * WW)            // 3136
#define KPOS 9
#define SCALE 0.17677669529663687f  // 32^-0.5
#define DSTR 36                   // LDS d-stride: 144 B (16B-aligned), conflict-free b128 reads
#define XCOLS 32                  // staged x-columns per block (28 outputs + 4 halo)
#define ROWF (XCOLS * DSTR)       // 1152 floats per staged row-plane
#define NROWS 4                   // staged rows {y0-2, y0, y0+2, y0+4}
#define PAIRS 14                  // same-parity row-pairs per parity
#define XOUT 28                   // output columns per block

// Block (256 thr) = (bh, parity, pair, x-half). Stages 4 k/v rows x 32 cols
// into LDS in d-CONTIGUOUS layout [r][x'][d] (stride 36), zero-pad baked in.
// Compute: thread = (w2, pxl, c): output row y0+2*w2, col x0+pxl, dims 8c..8c+7.
// All tap reads are 2x ds_read_b128. Softmax partials reduced over 4 c-lanes.
__global__ __launch_bounds__(256, 4) void dilate_attn_v7(
    const float* __restrict__ q,
    const float* __restrict__ k,
    const float* __restrict__ v,
    float* __restrict__ out)
{
    __shared__ __align__(16) float ks[NROWS * ROWF];   // 18,432 B
    __shared__ __align__(16) float vs[NROWS * ROWF];   // 18,432 B (total 36,864)

    // block id = ((parity*14 + p)*2 + xh)*48 + bh  -> reuse partners same XCD
    const int bh  = blockIdx.x % 48;
    const int r1  = blockIdx.x / 48;
    const int xh  = r1 & 1;
    const int pl  = r1 >> 1;                 // parity*14 + p
    const int parity = pl / PAIRS;
    const int p      = pl % PAIRS;
    const int y0  = 4 * p + parity;          // outputs y0, y0+2
    const int x0  = xh * XOUT;               // output cols x0..x0+27
    const int t   = threadIdx.x;

    const size_t plane = (size_t)bh * HEAD_DIM * HWSZ;

    // ---- compute-thread mapping (also used for q prefetch) ----
    const int w2  = t >> 7;                  // 0..1 -> output row y0 + 2*w2
    const int tt  = t & 127;
    const int pxl = tt >> 2;                 // 0..31 (valid < 28)
    const int c   = tt & 3;                  // dim-octet
    const int y   = y0 + 2 * w2;
    const int gx  = x0 + pxl;
    const bool active = pxl < XOUT;

    // ---- q prefetch (independent of LDS staging) ----
    float qreg[8];
    if (active) {
        const float* qb = q + plane + (size_t)(8 * c) * HWSZ + y * WW + gx;
#pragma unroll
        for (int j = 0; j < 8; j++) qreg[j] = qb[j * HWSZ];
    }

    // ---- stage 4 rows x 32 cols of k and v, transposed to [r][x][d] ----
#pragma unroll
    for (int i = 0; i < 16; i++) {           // 16*256 = 4096 = 4*32*32
        const int e = t + 256 * i;
        const int x = e & 31;
        const int d = (e >> 5) & 31;
        const int r = e >> 10;
        const int sy = y0 - 2 + 2 * r;
        const int sx = x0 - 2 + x;
        const bool ok = (sy >= 0) & (sy < HH) & (sx >= 0) & (sx < WW);
        const size_t g = plane + (size_t)d * HWSZ + (ok ? (sy * WW + sx) : 0);
        const float kvv = ok ? k[g] : 0.0f;
        const float vvv = ok ? v[g] : 0.0f;
        const int a = r * ROWF + x * DSTR + d;
        ks[a] = kvv;
        vs[a] = vvv;
    }
    __syncthreads();

    if (!active) return;                     // no further barriers

    // ---- QK^T: taps (rr, ix) -> staged row w2+rr, xloc = pxl + 2*ix ----
    float lg[KPOS];
#pragma unroll
    for (int rr = 0; rr < 3; rr++) {
#pragma unroll
        for (int ix = 0; ix < 3; ix++) {
            const float* kp = ks + (w2 + rr) * ROWF + (pxl + 2 * ix) * DSTR + 8 * c;
            const float4 k0 = *reinterpret_cast<const float4*>(kp);
            const float4 k1 = *reinterpret_cast<const float4*>(kp + 4);
            float a = qreg[0] * k0.x;
            a = fmaf(qreg[1], k0.y, a);
            a = fmaf(qreg[2], k0.z, a);
            a = fmaf(qreg[3], k0.w, a);
            a = fmaf(qreg[4], k1.x, a);
            a = fmaf(qreg[5], k1.y, a);
            a = fmaf(qreg[6], k1.z, a);
            a = fmaf(qreg[7], k1.w, a);
            lg[3 * rr + ix] = a;
        }
    }

    // ---- reduce partials over the 4 c-lanes (lanes 4*px .. 4*px+3) ----
#pragma unroll
    for (int kk = 0; kk < KPOS; kk++) {
        float s = lg[kk];
        s += __shfl_xor(s, 1);
        s += __shfl_xor(s, 2);
        lg[kk] = s * SCALE;
    }

    // ---- softmax over 9 taps (redundant per lane) ----
    float m = lg[0];
#pragma unroll
    for (int kk = 1; kk < KPOS; kk++) m = fmaxf(m, lg[kk]);
    float ssum = 0.f;
    float w[KPOS];
#pragma unroll
    for (int kk = 0; kk < KPOS; kk++) {
        w[kk] = __expf(lg[kk] - m);
        ssum += w[kk];
    }
    const float inv = 1.f / ssum;
#pragma unroll
    for (int kk = 0; kk < KPOS; kk++) w[kk] *= inv;

    // ---- PV: same tap pattern from vs ----
    float a0 = 0.f, a1 = 0.f, a2 = 0.f, a3 = 0.f;
    float a4 = 0.f, a5 = 0.f, a6 = 0.f, a7 = 0.f;
#pragma unroll
    for (int rr = 0; rr < 3; rr++) {
#pragma unroll
        for (int ix = 0; ix < 3; ix++) {
            const float* vp = vs + (w2 + rr) * ROWF + (pxl + 2 * ix) * DSTR + 8 * c;
            const float4 v0 = *reinterpret_cast<const float4*>(vp);
            const float4 v1 = *reinterpret_cast<const float4*>(vp + 4);
            const float wk = w[3 * rr + ix];
            a0 = fmaf(wk, v0.x, a0);
            a1 = fmaf(wk, v0.y, a1);
            a2 = fmaf(wk, v0.z, a2);
            a3 = fmaf(wk, v0.w, a3);
            a4 = fmaf(wk, v1.x, a4);
            a5 = fmaf(wk, v1.y, a5);
            a6 = fmaf(wk, v1.z, a6);
            a7 = fmaf(wk, v1.w, a7);
        }
    }

    // ---- store: out[b, y, gx, h*32 + 8c .. +7] ----
    const int h = bh % NH;
    const int b = bh / NH;
    float* ob = out + ((size_t)((b * HH + y) * WW + gx)) * CCH
                    + h * HEAD_DIM + 8 * c;
    reinterpret_cast<float4*>(ob)[0] = make_float4(a0, a1, a2, a3);
    reinterpret_cast<float4*>(ob)[1] = make_float4(a4, a5, a6, a7);
}

extern "C" void kernel_launch(void* const* d_in, const int* in_sizes, int n_in,
                              void* d_out, int out_size, void* d_ws, size_t ws_size,
                              hipStream_t stream) {
    const float* q = (const float*)d_in[0];
    const float* k = (const float*)d_in[1];
    const float* v = (const float*)d_in[2];
    float* out = (float*)d_out;

    const int blocks = 48 * 2 * PAIRS * 2;   // 2688
    dilate_attn_v7<<<blocks, 256, 0, stream>>>(q, k, v, out);
}

// Round 8
// 105.741 us; speedup vs baseline: 1.1160x; 1.1160x over previous
//
#include <hip/hip_runtime.h>

#define NH 6
#define HEAD_DIM 32
#define CCH 192
#define HH 56
#define WW 56
#define HWSZ (HH * WW)            // 3136
#define KPOS 9
#define SCALE 0.17677669529663687f  // 32^-0.5
#define XPAD 61                   // x-stride: conflict-free reads & writes (R5-proven)
#define ROWSZ (HEAD_DIM * XPAD)   // 1952 floats per staged row-plane
#define JROWS 4                   // output rows per block (same parity)
#define STRIPS 7                  // strips per parity (7*4 = 28 rows)

// Block = (bh, parity, strip). Outputs rows y0+2j, j=0..3. LDS = 3-slot ring
// of k/v row-planes in [d][x'] layout (XPAD 61, zero-pad baked in). Rolling
// schedule: prefetch row r=j+3 (and next q) into regs DURING compute of row j,
// commit to slot j%3 after the barrier. 672 blocks x 46.8KB = whole grid
// co-resident at 3 blocks/CU; every compute phase has loads in flight.
__global__ __launch_bounds__(256, 4) void dilate_attn_roll(
    const float* __restrict__ q,
    const float* __restrict__ k,
    const float* __restrict__ v,
    float* __restrict__ out)
{
    __shared__ float ks[3][ROWSZ];
    __shared__ float vs[3][ROWSZ];

    // bh fastest -> (bh, strip±1) partners 48 apart (same XCD, co-resident)
    const int bh     = blockIdx.x % 48;
    const int ps     = blockIdx.x / 48;
    const int parity = ps / STRIPS;
    const int s      = ps % STRIPS;
    const int y0     = parity + 8 * s;    // output rows y0 + 2j
    const int t      = threadIdx.x;

    const size_t plane = (size_t)bh * HEAD_DIM * HWSZ;
    const int px = t >> 2;                // 0..63 (valid < 56)
    const int c  = t & 3;                 // dim-octet
    const bool active = px < WW;

    // staging element map: 7 elems/thread per row (7*256 = 1792 = 32*56)
    int sd[7], sx[7];
#pragma unroll
    for (int i = 0; i < 7; i++) {
        const int e = t + 256 * i;
        sd[i] = e / WW;
        sx[i] = e - sd[i] * WW;
    }

    // ---- q for row 0 (issue first; overlaps prologue staging) ----
    float qcur[8];
    if (active) {
        const float* qb = q + plane + (size_t)(8 * c) * HWSZ + (size_t)y0 * WW + px;
#pragma unroll
        for (int j = 0; j < 8; j++) qcur[j] = qb[j * HWSZ];
    }

    // ---- zero pad columns x' in {0,1,58,59} for all 3 slots (done ONCE;
    //      row data never overwrites pads) ----
    for (int e = t; e < 3 * HEAD_DIM * 4; e += 256) {
        const int slot = e >> 7;
        const int rr   = e & 127;
        const int d    = rr >> 2;
        const int xc   = rr & 3;
        const int xp   = (xc < 2) ? xc : (56 + xc);
        ks[slot][d * XPAD + xp] = 0.0f;
        vs[slot][d * XPAD + xp] = 0.0f;
    }

    // ---- prologue: stage rows r=0,1,2 (ky = y0-2+2r) into slots 0,1,2 ----
    float kpre[7], vpre[7];
#pragma unroll
    for (int r = 0; r < 3; r++) {
        const int ky   = y0 - 2 + 2 * r;
        const bool okr = (ky >= 0) && (ky < HH);
#pragma unroll
        for (int i = 0; i < 7; i++) {
            const size_t g = plane + (size_t)sd[i] * HWSZ + (size_t)(okr ? ky : 0) * WW + sx[i];
            kpre[i] = okr ? k[g] : 0.0f;
            vpre[i] = okr ? v[g] : 0.0f;
        }
#pragma unroll
        for (int i = 0; i < 7; i++) {
            const int a = sd[i] * XPAD + sx[i] + 2;
            ks[r][a] = kpre[i];
            vs[r][a] = vpre[i];
        }
    }
    __syncthreads();

    // ---- main rolling loop over the 4 output rows ----
    float qnxt[8];
#pragma unroll
    for (int j = 0; j < JROWS; j++) {
        const int y = y0 + 2 * j;

        // prefetch staged row r=j+3 (ky = y0+4+2j) + next q into registers
        if (j < 3) {
            const int ky   = y0 + 4 + 2 * j;       // always >= 4
            const bool okr = (ky < HH);
#pragma unroll
            for (int i = 0; i < 7; i++) {
                const size_t g = plane + (size_t)sd[i] * HWSZ + (size_t)(okr ? ky : 0) * WW + sx[i];
                kpre[i] = okr ? k[g] : 0.0f;
                vpre[i] = okr ? v[g] : 0.0f;
            }
            if (active) {
                const float* qb = q + plane + (size_t)(8 * c) * HWSZ + (size_t)(y + 2) * WW + px;
#pragma unroll
                for (int jj = 0; jj < 8; jj++) qnxt[jj] = qb[jj * HWSZ];
            }
        }

        // compute output row j from slots (j+r')%3, r'=0..2 (loads in flight)
        if (active) {
            float lg[KPOS];
#pragma unroll
            for (int rp = 0; rp < 3; rp++) {
                const float* kr = &ks[(j + rp) % 3][(8 * c) * XPAD + px];
                float a0 = 0.f, a1 = 0.f, a2 = 0.f;
#pragma unroll
                for (int j8 = 0; j8 < 8; j8++) {
                    const float* p  = kr + j8 * XPAD;
                    const float qj = qcur[j8];
                    a0 = fmaf(qj, p[0], a0);
                    a1 = fmaf(qj, p[2], a1);
                    a2 = fmaf(qj, p[4], a2);
                }
                lg[3 * rp + 0] = a0;
                lg[3 * rp + 1] = a1;
                lg[3 * rp + 2] = a2;
            }
#pragma unroll
            for (int kk = 0; kk < KPOS; kk++) {
                float sm = lg[kk];
                sm += __shfl_xor(sm, 1);
                sm += __shfl_xor(sm, 2);
                lg[kk] = sm * SCALE;
            }
            float m = lg[0];
#pragma unroll
            for (int kk = 1; kk < KPOS; kk++) m = fmaxf(m, lg[kk]);
            float ssum = 0.f;
#pragma unroll
            for (int kk = 0; kk < KPOS; kk++) {
                lg[kk] = __expf(lg[kk] - m);
                ssum += lg[kk];
            }
            const float inv = 1.f / ssum;

            float acc[8];
#pragma unroll
            for (int jj = 0; jj < 8; jj++) acc[jj] = 0.f;
#pragma unroll
            for (int rp = 0; rp < 3; rp++) {
                const float* vr = &vs[(j + rp) % 3][(8 * c) * XPAD + px];
                const float w0 = lg[3 * rp + 0] * inv;
                const float w1 = lg[3 * rp + 1] * inv;
                const float w2 = lg[3 * rp + 2] * inv;
#pragma unroll
                for (int jj = 0; jj < 8; jj++) {
                    const float* p = vr + jj * XPAD;
                    float a = acc[jj];
                    a = fmaf(w0, p[0], a);
                    a = fmaf(w1, p[2], a);
                    a = fmaf(w2, p[4], a);
                    acc[jj] = a;
                }
            }

            const int h = bh % NH;
            const int b = bh / NH;
            float* ob = out + ((size_t)((b * HH + y) * WW + px)) * CCH
                            + h * HEAD_DIM + 8 * c;
            reinterpret_cast<float4*>(ob)[0] = make_float4(acc[0], acc[1], acc[2], acc[3]);
            reinterpret_cast<float4*>(ob)[1] = make_float4(acc[4], acc[5], acc[6], acc[7]);
        }

        __syncthreads();    // all waves done reading slot j%3

        if (j < 3) {
            // commit prefetched row r=j+3 into slot j%3; roll q
#pragma unroll
            for (int i = 0; i < 7; i++) {
                const int a = sd[i] * XPAD + sx[i] + 2;
                ks[j % 3][a] = kpre[i];
                vs[j % 3][a] = vpre[i];
            }
#pragma unroll
            for (int jj = 0; jj < 8; jj++) qcur[jj] = qnxt[jj];
        }

        __syncthreads();    // new slot contents visible before next compute
    }
}

extern "C" void kernel_launch(void* const* d_in, const int* in_sizes, int n_in,
                              void* d_out, int out_size, void* d_ws, size_t ws_size,
                              hipStream_t stream) {
    const float* q = (const float*)d_in[0];
    const float* k = (const float*)d_in[1];
    const float* v = (const float*)d_in[2];
    float* out = (float*)d_out;

    const int blocks = 48 * 2 * STRIPS;   // 672 — fully co-resident at 3/CU
    dilate_attn_roll<<<blocks, 256, 0, stream>>>(q, k, v, out);
}